// Round 3
// baseline (1257.149 us; speedup 1.0000x reference)
//
#include <hip/hip_runtime.h>
#include <stdint.h>

#define D_IN   4096
#define D_OUT  4096
#define MROWS  8192                  // 4 * 2048
#define NW     (D_OUT * D_IN)        // 16777216 weight elements
#define STD_K  1.6

typedef float  f32x4v  __attribute__((ext_vector_type(4)));
typedef __bf16 bf16x8  __attribute__((ext_vector_type(8)));

// ---------- bf16 helpers (RNE) ----------
__device__ __forceinline__ unsigned short f2bf(float f) {
    unsigned int u = __float_as_uint(f);
    u = u + 0x7fffu + ((u >> 16) & 1u);   // round-to-nearest-even
    return (unsigned short)(u >> 16);
}
__device__ __forceinline__ float bf2f(unsigned short b) {
    return __uint_as_float(((unsigned int)b) << 16);
}

// ---------- async global->LDS (16B/lane, dest = wave-uniform base + lane*16) ----------
__device__ __forceinline__ void gload_lds16(const void* g, void* l) {
    __builtin_amdgcn_global_load_lds(
        (__attribute__((address_space(1))) void*)(void*)(g),
        (__attribute__((address_space(3))) void*)(l),
        16, 0, 0);
}

// ---------- stats pass 1: sum, sumsq (f64 accumulate) ----------
__global__ void k_stats1(const float* __restrict__ w, double* __restrict__ stats) {
    const int n4 = NW / 4;
    const float4* w4 = (const float4*)w;
    double s = 0.0, s2 = 0.0;
    for (int i = blockIdx.x * blockDim.x + threadIdx.x; i < n4;
         i += gridDim.x * blockDim.x) {
        float4 v = w4[i];
        s  += (double)v.x + (double)v.y + (double)v.z + (double)v.w;
        s2 += (double)v.x * (double)v.x + (double)v.y * (double)v.y +
              (double)v.z * (double)v.z + (double)v.w * (double)v.w;
    }
    for (int o = 32; o; o >>= 1) { s += __shfl_down(s, o); s2 += __shfl_down(s2, o); }
    if ((threadIdx.x & 63) == 0) {
        atomicAdd(&stats[0], s);
        atomicAdd(&stats[1], s2);
    }
}

__device__ __forceinline__ void thresholds(const double* stats, double& lo, double& hi) {
    const double n = (double)NW;
    double mean = stats[0] / n;
    double var  = (stats[1] - stats[0] * mean) / (n - 1.0);   // ddof=1, exact algebra
    double sd   = sqrt(var);
    lo = mean - STD_K * sd;
    hi = mean + STD_K * sd;
}

// ---------- stats pass 2: sum(|w| * keep), count(keep) ----------
__global__ void k_stats2(const float* __restrict__ w, double* __restrict__ stats) {
    double lo, hi;
    thresholds(stats, lo, hi);
    const int n4 = NW / 4;
    const float4* w4 = (const float4*)w;
    double sa = 0.0, cnt = 0.0;
#define ACC1(X) { bool keep = ((double)(X) >= lo) && ((double)(X) <= hi); \
                  if (keep) { sa += (double)fabsf(X); cnt += 1.0; } }
    for (int i = blockIdx.x * blockDim.x + threadIdx.x; i < n4;
         i += gridDim.x * blockDim.x) {
        float4 v = w4[i];
        ACC1(v.x) ACC1(v.y) ACC1(v.z) ACC1(v.w)
    }
#undef ACC1
    for (int o = 32; o; o >>= 1) { sa += __shfl_down(sa, o); cnt += __shfl_down(cnt, o); }
    if ((threadIdx.x & 63) == 0) {
        atomicAdd(&stats[2], sa);
        atomicAdd(&stats[3], cnt);
    }
}

// ---------- weight transform -> W_hi / W_lo (bf16 split of w_sim) ----------
__device__ __forceinline__ void split1(float x, double lo, double hi, float s,
                                       unsigned short& h, unsigned short& l) {
    bool outl = ((double)x < lo) || ((double)x > hi);
    float sg   = (x > 0.f) ? s : ((x < 0.f) ? -s : 0.f);
    float wsim = outl ? x : sg;
    unsigned short hb = f2bf(wsim);
    h = hb;
    l = f2bf(wsim - bf2f(hb));
}

__global__ void k_wsplit(const float* __restrict__ w, const double* __restrict__ stats,
                         ushort4* __restrict__ Whi, ushort4* __restrict__ Wlo) {
    double lo, hi;
    thresholds(stats, lo, hi);
    float s = (float)(stats[2] / stats[3]);
    const int n4 = NW / 4;
    const float4* w4 = (const float4*)w;
    for (int i = blockIdx.x * blockDim.x + threadIdx.x; i < n4;
         i += gridDim.x * blockDim.x) {
        float4 v = w4[i];
        ushort4 h, l;
        split1(v.x, lo, hi, s, h.x, l.x);
        split1(v.y, lo, hi, s, h.y, l.y);
        split1(v.z, lo, hi, s, h.z, l.z);
        split1(v.w, lo, hi, s, h.w, l.w);
        Whi[i] = h; Wlo[i] = l;
    }
}

// ---------- x -> X_hi / X_lo (bf16 split) ----------
__global__ void k_xsplit(const float* __restrict__ x,
                         ushort4* __restrict__ Xh, ushort4* __restrict__ Xl) {
    const int n4 = (MROWS * D_IN) / 4;
    const float4* x4 = (const float4*)x;
    for (int i = blockIdx.x * blockDim.x + threadIdx.x; i < n4;
         i += gridDim.x * blockDim.x) {
        float4 v = x4[i];
        ushort4 h, l;
        h.x = f2bf(v.x); l.x = f2bf(v.x - bf2f(h.x));
        h.y = f2bf(v.y); l.y = f2bf(v.y - bf2f(h.y));
        h.z = f2bf(v.z); l.z = f2bf(v.z - bf2f(h.z));
        h.w = f2bf(v.w); l.w = f2bf(v.w - bf2f(h.w));
        Xh[i] = h; Xl[i] = l;
    }
}

// ---------- GEMM: out = Xh@Wh^T + Xl@Wh^T + Xh@Wl^T + bias ----------
// 128x128 tile, BK=64, 4 waves (2x2), each wave 64x64 via 4x4 frags of 16x16x32.
// 4-tile staging per K-step (Xh,Xl,Wh,Wl) -> 96 MFMA per barrier pair,
// 0.67x staged bytes per MFMA vs 3 sequential segment GEMMs.
// 1-D grid of 2048 blocks with bijective XCD swizzle (T1; 2048 % 8 == 0).
#define GEMM_NWG   ((MROWS / 128) * (D_OUT / 128))   // 64 * 32 = 2048
#define NXCD       8
#define CPX        (GEMM_NWG / NXCD)                  // 256

__global__ __launch_bounds__(256, 2) void k_gemm(
    const unsigned short* __restrict__ Xh, const unsigned short* __restrict__ Xl,
    const unsigned short* __restrict__ Wh, const unsigned short* __restrict__ Wl,
    const float* __restrict__ bias, float* __restrict__ out)
{
    // 4 x 16 KiB = 64 KiB LDS -> 2 blocks/CU; linear row-major [128][64] (128 B rows)
    __shared__ unsigned short AsH[128 * 64];
    __shared__ unsigned short AsL[128 * 64];
    __shared__ unsigned short BsH[128 * 64];
    __shared__ unsigned short BsL[128 * 64];

    // XCD-aware swizzle: give each XCD a contiguous slab of blocks (L2 locality).
    const int bid = blockIdx.x;
    const int swz = (bid % NXCD) * CPX + bid / NXCD;
    const int bx  = swz & 31;        // output-col block  (32 of them)
    const int by  = swz >> 5;        // output-row block  (64 of them)

    const int tid  = threadIdx.x;
    const int wave = tid >> 6, lane = tid & 63;
    const int wr = wave >> 1, wc = wave & 1;      // 2x2 wave grid
    const int fcol = lane & 15, fk = lane >> 4;   // fragment lane decomposition
    const int brow = by * 128, bcol = bx * 128;

    f32x4v acc[4][4];
    const f32x4v zero = {0.f, 0.f, 0.f, 0.f};
#pragma unroll
    for (int m = 0; m < 4; m++)
#pragma unroll
        for (int n = 0; n < 4; n++) acc[m][n] = zero;

    const unsigned short* Agh = Xh + (size_t)brow * D_IN;
    const unsigned short* Agl = Xl + (size_t)brow * D_IN;
    const unsigned short* Bgh = Wh + (size_t)bcol * D_IN;
    const unsigned short* Bgl = Wl + (size_t)bcol * D_IN;

    const int srow = wave * 8 + (lane >> 3);   // staging row within 32-row chunk
    const int scol = (lane & 7) * 8;           // staging col (8 bf16 = 16B)

    for (int kk = 0; kk < D_IN; kk += 64) {
        // stage 4 tiles: 16 instrs/wave; each instr = 64 lanes x 16B = 8 rows
#pragma unroll
        for (int i = 0; i < 4; i++) {
            const size_t goff = (size_t)(i * 32 + srow) * D_IN + kk + scol;
            const int    loff = (i * 32 + wave * 8) * 128;
            gload_lds16(Agh + goff, (char*)AsH + loff);
            gload_lds16(Agl + goff, (char*)AsL + loff);
            gload_lds16(Bgh + goff, (char*)BsH + loff);
            gload_lds16(Bgl + goff, (char*)BsL + loff);
        }
        __syncthreads();   // compiler drains vmcnt before s_barrier

#pragma unroll
        for (int k2 = 0; k2 < 2; k2++) {
            bf16x8 ah[4], al[4], bh[4], bl[4];
#pragma unroll
            for (int m = 0; m < 4; m++) {
                const int ro = (wr * 64 + m * 16 + fcol) * 64 + k2 * 32 + fk * 8;
                ah[m] = *(const bf16x8*)&AsH[ro];
                al[m] = *(const bf16x8*)&AsL[ro];
            }
#pragma unroll
            for (int n = 0; n < 4; n++) {
                const int ro = (wc * 64 + n * 16 + fcol) * 64 + k2 * 32 + fk * 8;
                bh[n] = *(const bf16x8*)&BsH[ro];
                bl[n] = *(const bf16x8*)&BsL[ro];
            }
            // all three products accumulate into the SAME acc (single output sum)
#pragma unroll
            for (int m = 0; m < 4; m++)
#pragma unroll
                for (int n = 0; n < 4; n++) {
                    acc[m][n] = __builtin_amdgcn_mfma_f32_16x16x32_bf16(
                        ah[m], bh[n], acc[m][n], 0, 0, 0);
                    acc[m][n] = __builtin_amdgcn_mfma_f32_16x16x32_bf16(
                        al[m], bh[n], acc[m][n], 0, 0, 0);
                    acc[m][n] = __builtin_amdgcn_mfma_f32_16x16x32_bf16(
                        ah[m], bl[n], acc[m][n], 0, 0, 0);
                }
        }
        __syncthreads();
    }

    // epilogue: C/D mapping col=lane&15, row=(lane>>4)*4+reg  [m89-verified]
#pragma unroll
    for (int n = 0; n < 4; n++) {
        int col = bcol + wc * 64 + n * 16 + fcol;
        float bv = bias[col];
#pragma unroll
        for (int m = 0; m < 4; m++) {
            int row = brow + wr * 64 + m * 16 + fk * 4;
            float* o = out + (size_t)row * D_OUT + col;
#pragma unroll
            for (int r = 0; r < 4; r++) o[(size_t)r * D_OUT] = acc[m][n][r] + bv;
        }
    }
}

// ---------- launch ----------
extern "C" void kernel_launch(void* const* d_in, const int* in_sizes, int n_in,
                              void* d_out, int out_size, void* d_ws, size_t ws_size,
                              hipStream_t stream) {
    const float* x    = (const float*)d_in[0];   // [8192, 4096]
    const float* w    = (const float*)d_in[1];   // [4096, 4096]
    const float* bias = (const float*)d_in[2];   // [4096]
    float* out = (float*)d_out;                  // [8192, 4096]

    char* ws = (char*)d_ws;
    double* stats = (double*)ws;                                    // 4 doubles
    unsigned short* Whi = (unsigned short*)(ws + 256);              // 32 MiB
    unsigned short* Wlo = Whi + (size_t)NW;                         // 32 MiB
    unsigned short* Xh  = (unsigned short*)(ws + 256 + (size_t)2 * NW * 2);  // 64 MiB
    unsigned short* Xl  = Xh + (size_t)MROWS * D_IN;                // 64 MiB
    // total ws need: ~192 MiB + 256 B

    hipMemsetAsync(stats, 0, 4 * sizeof(double), stream);
    k_stats1<<<1024, 256, 0, stream>>>(w, stats);
    k_stats2<<<1024, 256, 0, stream>>>(w, stats);
    k_wsplit<<<1024, 256, 0, stream>>>(w, stats, (ushort4*)Whi, (ushort4*)Wlo);
    k_xsplit<<<2048, 256, 0, stream>>>(x, (ushort4*)Xh, (ushort4*)Xl);

    k_gemm<<<GEMM_NWG, 256, 0, stream>>>(Xh, Xl, Whi, Wlo, bias, out);
}

// Round 6
// 1029.677 us; speedup vs baseline: 1.2209x; 1.2209x over previous
//
#include <hip/hip_runtime.h>
#include <stdint.h>

#define D_IN   4096
#define D_OUT  4096
#define MROWS  8192                  // 4 * 2048
#define NW     (D_OUT * D_IN)        // 16777216 weight elements
#define NX     (MROWS * D_IN)        // 33554432 x elements
#define STD_K  1.6

typedef float  f32x4v  __attribute__((ext_vector_type(4)));
typedef __bf16 bf16x8  __attribute__((ext_vector_type(8)));

// ---------- bf16 helpers (RNE) ----------
__device__ __forceinline__ unsigned short f2bf(float f) {
    unsigned int u = __float_as_uint(f);
    u = u + 0x7fffu + ((u >> 16) & 1u);   // round-to-nearest-even
    return (unsigned short)(u >> 16);
}
__device__ __forceinline__ float bf2f(unsigned short b) {
    return __uint_as_float(((unsigned int)b) << 16);
}

// ---------- async global->LDS (16B/lane, dest = wave-uniform base + lane*16) ----------
__device__ __forceinline__ void gload_lds16(const void* g, void* l) {
    __builtin_amdgcn_global_load_lds(
        (__attribute__((address_space(1))) void*)(void*)(g),
        (__attribute__((address_space(3))) void*)(l),
        16, 0, 0);
}

// ================= preprocessing (atomic-free) =================
#define ST_BLK 512                    // stats blocks
// pre1: blocks [0,512) do stats1 partials over w; blocks [512,2560) do xsplit.
__global__ void k_pre1(const float* __restrict__ w, const float* __restrict__ x,
                       double* __restrict__ part1,
                       ushort4* __restrict__ Xh, ushort4* __restrict__ Xl) {
    __shared__ double red[8];
    const int tid = threadIdx.x;
    if (blockIdx.x < ST_BLK) {
        const int n4 = NW / 4;
        const float4* w4 = (const float4*)w;
        double s = 0.0, s2 = 0.0;
        for (int i = blockIdx.x * 256 + tid; i < n4; i += ST_BLK * 256) {
            float4 v = w4[i];
            s  += (double)v.x + (double)v.y + (double)v.z + (double)v.w;
            s2 += (double)v.x * (double)v.x + (double)v.y * (double)v.y +
                  (double)v.z * (double)v.z + (double)v.w * (double)v.w;
        }
        for (int o = 32; o; o >>= 1) { s += __shfl_down(s, o); s2 += __shfl_down(s2, o); }
        const int wave = tid >> 6, lane = tid & 63;
        if (lane == 0) { red[wave] = s; red[4 + wave] = s2; }
        __syncthreads();
        if (tid == 0) {
            part1[2 * blockIdx.x]     = red[0] + red[1] + red[2] + red[3];
            part1[2 * blockIdx.x + 1] = red[4] + red[5] + red[6] + red[7];
        }
    } else {
        const int n4 = NX / 4;
        const float4* x4 = (const float4*)x;
        for (int i = (blockIdx.x - ST_BLK) * 256 + tid; i < n4; i += 2048 * 256) {
            float4 v = x4[i];
            ushort4 h, l;
            h.x = f2bf(v.x); l.x = f2bf(v.x - bf2f(h.x));
            h.y = f2bf(v.y); l.y = f2bf(v.y - bf2f(h.y));
            h.z = f2bf(v.z); l.z = f2bf(v.z - bf2f(h.z));
            h.w = f2bf(v.w); l.w = f2bf(v.w - bf2f(h.w));
            Xh[i] = h; Xl[i] = l;
        }
    }
}

// reduce 512 partial pairs -> out2[0], out2[1]   (1 block, 256 threads)
__global__ void k_red(const double* __restrict__ part, double* __restrict__ out2) {
    const int t = threadIdx.x;
    double s  = part[2 * t]     + part[2 * (t + 256)];
    double s2 = part[2 * t + 1] + part[2 * (t + 256) + 1];
    for (int o = 32; o; o >>= 1) { s += __shfl_down(s, o); s2 += __shfl_down(s2, o); }
    __shared__ double red[8];
    const int wave = t >> 6, lane = t & 63;
    if (lane == 0) { red[wave] = s; red[4 + wave] = s2; }
    __syncthreads();
    if (t == 0) {
        out2[0] = red[0] + red[1] + red[2] + red[3];
        out2[1] = red[4] + red[5] + red[6] + red[7];
    }
}

__device__ __forceinline__ void thresholds(const double* stats, double& lo, double& hi) {
    const double n = (double)NW;
    double mean = stats[0] / n;
    double var  = (stats[1] - stats[0] * mean) / (n - 1.0);   // ddof=1, exact algebra
    double sd   = sqrt(var);
    lo = mean - STD_K * sd;
    hi = mean + STD_K * sd;
}

// stats pass 2 partials: sum(|w| * keep), count(keep)
__global__ void k_stats2(const float* __restrict__ w, const double* __restrict__ stats,
                         double* __restrict__ part2) {
    double lo, hi;
    thresholds(stats, lo, hi);
    const int n4 = NW / 4;
    const float4* w4 = (const float4*)w;
    double sa = 0.0, cnt = 0.0;
#define ACC1(X) { bool keep = ((double)(X) >= lo) && ((double)(X) <= hi); \
                  if (keep) { sa += (double)fabsf(X); cnt += 1.0; } }
    for (int i = blockIdx.x * 256 + threadIdx.x; i < n4; i += ST_BLK * 256) {
        float4 v = w4[i];
        ACC1(v.x) ACC1(v.y) ACC1(v.z) ACC1(v.w)
    }
#undef ACC1
    for (int o = 32; o; o >>= 1) { sa += __shfl_down(sa, o); cnt += __shfl_down(cnt, o); }
    __shared__ double red[8];
    const int wave = threadIdx.x >> 6, lane = threadIdx.x & 63;
    if (lane == 0) { red[wave] = sa; red[4 + wave] = cnt; }
    __syncthreads();
    if (threadIdx.x == 0) {
        part2[2 * blockIdx.x]     = red[0] + red[1] + red[2] + red[3];
        part2[2 * blockIdx.x + 1] = red[4] + red[5] + red[6] + red[7];
    }
}

// ---------- weight transform -> W_hi / W_lo (bf16 split of w_sim) ----------
__device__ __forceinline__ void split1(float x, double lo, double hi, float s,
                                       unsigned short& h, unsigned short& l) {
    bool outl = ((double)x < lo) || ((double)x > hi);
    float sg   = (x > 0.f) ? s : ((x < 0.f) ? -s : 0.f);
    float wsim = outl ? x : sg;
    unsigned short hb = f2bf(wsim);
    h = hb;
    l = f2bf(wsim - bf2f(hb));
}

__global__ void k_wsplit(const float* __restrict__ w, const double* __restrict__ stats,
                         ushort4* __restrict__ Whi, ushort4* __restrict__ Wlo) {
    double lo, hi;
    thresholds(stats, lo, hi);
    float s = (float)(stats[2] / stats[3]);
    const int n4 = NW / 4;
    const float4* w4 = (const float4*)w;
    for (int i = blockIdx.x * blockDim.x + threadIdx.x; i < n4;
         i += gridDim.x * blockDim.x) {
        float4 v = w4[i];
        ushort4 h, l;
        split1(v.x, lo, hi, s, h.x, l.x);
        split1(v.y, lo, hi, s, h.y, l.y);
        split1(v.z, lo, hi, s, h.z, l.z);
        split1(v.w, lo, hi, s, h.w, l.w);
        Whi[i] = h; Wlo[i] = l;
    }
}

// ================= GEMM =================
// out = Xh@Wh^T + Xl@Wh^T + Xh@Wl^T + bias
// 128x128 tile, BK=64, 4 waves (2x2), 4-tile staging, 96 MFMA per barrier pair.
// T2 XOR-swizzle (both-sides, rule #21): LDS dest stays linear for
// global_load_lds; the per-lane GLOBAL source is pre-swizzled so that logical
// 16B-slot q of row r lands at physical slot q^(r&7); readers XOR the same key.
// Per fk-quarter-wave the 16 lanes then cover all 8 slots (2/slot = free).
#define GEMM_NWG   ((MROWS / 128) * (D_OUT / 128))   // 64 * 32 = 2048
#define NXCD       8
#define CPX        (GEMM_NWG / NXCD)                  // 256

__global__ __launch_bounds__(256, 2) void k_gemm(
    const unsigned short* __restrict__ Xh, const unsigned short* __restrict__ Xl,
    const unsigned short* __restrict__ Wh, const unsigned short* __restrict__ Wl,
    const float* __restrict__ bias, float* __restrict__ out)
{
    __shared__ unsigned short AsH[128 * 64];
    __shared__ unsigned short AsL[128 * 64];
    __shared__ unsigned short BsH[128 * 64];
    __shared__ unsigned short BsL[128 * 64];

    const int bid = blockIdx.x;
    const int swz = (bid % NXCD) * CPX + bid / NXCD;  // bijective (2048 % 8 == 0)
    const int bx  = swz & 31;
    const int by  = swz >> 5;

    const int tid  = threadIdx.x;
    const int wave = tid >> 6, lane = tid & 63;
    const int wr = wave >> 1, wc = wave & 1;
    const int fcol = lane & 15, fk = lane >> 4;
    const int key  = fcol & 7;                    // reader swizzle key (= row&7)
    const int brow = by * 128, bcol = bx * 128;

    f32x4v acc[4][4];
    const f32x4v zero = {0.f, 0.f, 0.f, 0.f};
#pragma unroll
    for (int m = 0; m < 4; m++)
#pragma unroll
        for (int n = 0; n < 4; n++) acc[m][n] = zero;

    const unsigned short* Agh = Xh + (size_t)brow * D_IN;
    const unsigned short* Agl = Xl + (size_t)brow * D_IN;
    const unsigned short* Bgh = Wh + (size_t)bcol * D_IN;
    const unsigned short* Bgl = Wl + (size_t)bcol * D_IN;

    const int l8   = lane >> 3;                   // row within 8-row stripe
    const int q    = (lane & 7) ^ l8;             // pre-swizzled source slot
    const int srow = wave * 8 + l8;               // staging row within 32-row chunk
    const int scol = q * 8;                       // source col (8 bf16 = 16B)

    for (int kk = 0; kk < D_IN; kk += 64) {
#pragma unroll
        for (int i = 0; i < 4; i++) {
            const size_t goff = (size_t)(i * 32 + srow) * D_IN + kk + scol;
            const int    loff = (i * 32 + wave * 8) * 128;   // linear dest
            gload_lds16(Agh + goff, (char*)AsH + loff);
            gload_lds16(Agl + goff, (char*)AsL + loff);
            gload_lds16(Bgh + goff, (char*)BsH + loff);
            gload_lds16(Bgl + goff, (char*)BsL + loff);
        }
        __syncthreads();

#pragma unroll
        for (int k2 = 0; k2 < 2; k2++) {
            bf16x8 ah[4], al[4], bh[4], bl[4];
#pragma unroll
            for (int m = 0; m < 4; m++) {
                const int ro = (wr * 64 + m * 16 + fcol) * 64
                             + (((k2 * 4 + fk) ^ key) * 8);   // swizzled read
                ah[m] = *(const bf16x8*)&AsH[ro];
                al[m] = *(const bf16x8*)&AsL[ro];
            }
#pragma unroll
            for (int n = 0; n < 4; n++) {
                const int ro = (wc * 64 + n * 16 + fcol) * 64
                             + (((k2 * 4 + fk) ^ key) * 8);
                bh[n] = *(const bf16x8*)&BsH[ro];
                bl[n] = *(const bf16x8*)&BsL[ro];
            }
#pragma unroll
            for (int m = 0; m < 4; m++)
#pragma unroll
                for (int n = 0; n < 4; n++) {
                    acc[m][n] = __builtin_amdgcn_mfma_f32_16x16x32_bf16(
                        ah[m], bh[n], acc[m][n], 0, 0, 0);
                    acc[m][n] = __builtin_amdgcn_mfma_f32_16x16x32_bf16(
                        al[m], bh[n], acc[m][n], 0, 0, 0);
                    acc[m][n] = __builtin_amdgcn_mfma_f32_16x16x32_bf16(
                        ah[m], bl[n], acc[m][n], 0, 0, 0);
                }
        }
        __syncthreads();
    }

    // epilogue: C/D mapping col=lane&15, row=(lane>>4)*4+reg  [m89-verified]
#pragma unroll
    for (int n = 0; n < 4; n++) {
        int col = bcol + wc * 64 + n * 16 + fcol;
        float bv = bias[col];
#pragma unroll
        for (int m = 0; m < 4; m++) {
            int row = brow + wr * 64 + m * 16 + fk * 4;
            float* o = out + (size_t)row * D_OUT + col;
#pragma unroll
            for (int r = 0; r < 4; r++) o[(size_t)r * D_OUT] = acc[m][n][r] + bv;
        }
    }
}

// ---------- launch ----------
extern "C" void kernel_launch(void* const* d_in, const int* in_sizes, int n_in,
                              void* d_out, int out_size, void* d_ws, size_t ws_size,
                              hipStream_t stream) {
    const float* x    = (const float*)d_in[0];   // [8192, 4096]
    const float* w    = (const float*)d_in[1];   // [4096, 4096]
    const float* bias = (const float*)d_in[2];   // [4096]
    float* out = (float*)d_out;                  // [8192, 4096]

    char* ws = (char*)d_ws;
    double* part1 = (double*)ws;                         // 512*2 doubles = 8 KiB
    double* part2 = part1 + 2 * ST_BLK;                  // 8 KiB
    double* stats = part2 + 2 * ST_BLK;                  // 4 doubles
    unsigned short* Whi = (unsigned short*)(ws + 65536);            // 32 MiB
    unsigned short* Wlo = Whi + (size_t)NW;                         // 32 MiB
    unsigned short* Xh  = Wlo + (size_t)NW;                         // 64 MiB
    unsigned short* Xl  = Xh + (size_t)NX;                          // 64 MiB
    // total ws need: ~192 MiB + 64 KiB

    k_pre1  <<<ST_BLK + 2048, 256, 0, stream>>>(w, x, part1, (ushort4*)Xh, (ushort4*)Xl);
    k_red   <<<1, 256, 0, stream>>>(part1, stats);          // -> stats[0..1]
    k_stats2<<<ST_BLK, 256, 0, stream>>>(w, stats, part2);
    k_red   <<<1, 256, 0, stream>>>(part2, stats + 2);      // -> stats[2..3]
    k_wsplit<<<1024, 256, 0, stream>>>(w, stats, (ushort4*)Whi, (ushort4*)Wlo);

    k_gemm<<<GEMM_NWG, 256, 0, stream>>>(Xh, Xl, Whi, Wlo, bias, out);
}

// Round 7
// 1016.256 us; speedup vs baseline: 1.2370x; 1.0132x over previous
//
#include <hip/hip_runtime.h>
#include <stdint.h>

#define D_IN   4096
#define D_OUT  4096
#define MROWS  8192                  // 4 * 2048
#define NW     (D_OUT * D_IN)        // 16777216 weight elements
#define NX     (MROWS * D_IN)        // 33554432 x elements
#define STD_K  1.6

typedef float  f32x4v  __attribute__((ext_vector_type(4)));
typedef __bf16 bf16x8  __attribute__((ext_vector_type(8)));

// ---------- bf16 helpers (RNE) ----------
__device__ __forceinline__ unsigned short f2bf(float f) {
    unsigned int u = __float_as_uint(f);
    u = u + 0x7fffu + ((u >> 16) & 1u);
    return (unsigned short)(u >> 16);
}
__device__ __forceinline__ float bf2f(unsigned short b) {
    return __uint_as_float(((unsigned int)b) << 16);
}

// ---------- async global->LDS (16B/lane, dest = wave-uniform base + lane*16) ----------
__device__ __forceinline__ void gload_lds16(const void* g, void* l) {
    __builtin_amdgcn_global_load_lds(
        (__attribute__((address_space(1))) void*)(void*)(g),
        (__attribute__((address_space(3))) void*)(l),
        16, 0, 0);
}

// ================= preprocessing (atomic-free, k_red folded into consumers) ==
#define ST_BLK 512
#define XS_BLK 1536
// pre1: blocks [0,512) stats1 partials over w; blocks [512,2048) xsplit.
__global__ void k_pre1(const float* __restrict__ w, const float* __restrict__ x,
                       double* __restrict__ part1,
                       ushort4* __restrict__ Xh, ushort4* __restrict__ Xl) {
    __shared__ double red[8];
    const int tid = threadIdx.x;
    if (blockIdx.x < ST_BLK) {
        const int n4 = NW / 4;
        const float4* w4 = (const float4*)w;
        double s = 0.0, s2 = 0.0;
        for (int i = blockIdx.x * 256 + tid; i < n4; i += ST_BLK * 256) {
            float4 v = w4[i];
            s  += (double)v.x + (double)v.y + (double)v.z + (double)v.w;
            s2 += (double)v.x * (double)v.x + (double)v.y * (double)v.y +
                  (double)v.z * (double)v.z + (double)v.w * (double)v.w;
        }
        for (int o = 32; o; o >>= 1) { s += __shfl_down(s, o); s2 += __shfl_down(s2, o); }
        const int wave = tid >> 6, lane = tid & 63;
        if (lane == 0) { red[wave] = s; red[4 + wave] = s2; }
        __syncthreads();
        if (tid == 0) {
            part1[2 * blockIdx.x]     = red[0] + red[1] + red[2] + red[3];
            part1[2 * blockIdx.x + 1] = red[4] + red[5] + red[6] + red[7];
        }
    } else {
        const int n4 = NX / 4;
        const float4* x4 = (const float4*)x;
        for (int i = (blockIdx.x - ST_BLK) * 256 + tid; i < n4; i += XS_BLK * 256) {
            float4 v = x4[i];
            ushort4 h, l;
            h.x = f2bf(v.x); l.x = f2bf(v.x - bf2f(h.x));
            h.y = f2bf(v.y); l.y = f2bf(v.y - bf2f(h.y));
            h.z = f2bf(v.z); l.z = f2bf(v.z - bf2f(h.z));
            h.w = f2bf(v.w); l.w = f2bf(v.w - bf2f(h.w));
            Xh[i] = h; Xl[i] = l;
        }
    }
}

// in-block reduction of a [n][2] partial array -> tot[0], tot[1] (all threads see)
__device__ __forceinline__ void reduce_parts(const double* __restrict__ part, int n,
                                             double* __restrict__ tot /*shared[2]*/,
                                             double* __restrict__ red /*shared[8]*/) {
    const int tid = threadIdx.x;
    double s = 0.0, s2 = 0.0;
    for (int i = tid; i < n; i += 256) { s += part[2 * i]; s2 += part[2 * i + 1]; }
    for (int o = 32; o; o >>= 1) { s += __shfl_down(s, o); s2 += __shfl_down(s2, o); }
    const int wave = tid >> 6, lane = tid & 63;
    if (lane == 0) { red[wave] = s; red[4 + wave] = s2; }
    __syncthreads();
    if (tid == 0) {
        tot[0] = red[0] + red[1] + red[2] + red[3];
        tot[1] = red[4] + red[5] + red[6] + red[7];
    }
    __syncthreads();
}

__device__ __forceinline__ void thr_from(double s0, double s1, double& lo, double& hi) {
    const double n = (double)NW;
    double mean = s0 / n;
    double var  = (s1 - s0 * mean) / (n - 1.0);   // ddof=1
    double sd   = sqrt(var);
    lo = mean - STD_K * sd;
    hi = mean + STD_K * sd;
}

// stats2: reduce part1 in-block, then sum(|w|*keep), count(keep) partials
__global__ void k_stats2(const float* __restrict__ w, const double* __restrict__ part1,
                         double* __restrict__ part2) {
    __shared__ double red[8];
    __shared__ double tot[2];
    reduce_parts(part1, ST_BLK, tot, red);
    double lo, hi;
    thr_from(tot[0], tot[1], lo, hi);
    const int n4 = NW / 4;
    const float4* w4 = (const float4*)w;
    double sa = 0.0, cnt = 0.0;
#define ACC1(X) { bool keep = ((double)(X) >= lo) && ((double)(X) <= hi); \
                  if (keep) { sa += (double)fabsf(X); cnt += 1.0; } }
    for (int i = blockIdx.x * 256 + threadIdx.x; i < n4; i += ST_BLK * 256) {
        float4 v = w4[i];
        ACC1(v.x) ACC1(v.y) ACC1(v.z) ACC1(v.w)
    }
#undef ACC1
    for (int o = 32; o; o >>= 1) { sa += __shfl_down(sa, o); cnt += __shfl_down(cnt, o); }
    __syncthreads();
    const int wave = threadIdx.x >> 6, lane = threadIdx.x & 63;
    if (lane == 0) { red[wave] = sa; red[4 + wave] = cnt; }
    __syncthreads();
    if (threadIdx.x == 0) {
        part2[2 * blockIdx.x]     = red[0] + red[1] + red[2] + red[3];
        part2[2 * blockIdx.x + 1] = red[4] + red[5] + red[6] + red[7];
    }
}

__device__ __forceinline__ void split1(float x, double lo, double hi, float s,
                                       unsigned short& h, unsigned short& l) {
    bool outl = ((double)x < lo) || ((double)x > hi);
    float sg   = (x > 0.f) ? s : ((x < 0.f) ? -s : 0.f);
    float wsim = outl ? x : sg;
    unsigned short hb = f2bf(wsim);
    h = hb;
    l = f2bf(wsim - bf2f(hb));
}

// wsplit: reduce part1 (thresholds) + part2 (scale) in-block, then transform
__global__ void k_wsplit(const float* __restrict__ w, const double* __restrict__ part1,
                         const double* __restrict__ part2,
                         ushort4* __restrict__ Whi, ushort4* __restrict__ Wlo) {
    __shared__ double red[8];
    __shared__ double tot1[2];
    __shared__ double tot2[2];
    reduce_parts(part1, ST_BLK, tot1, red);
    __syncthreads();
    reduce_parts(part2, ST_BLK, tot2, red);
    double lo, hi;
    thr_from(tot1[0], tot1[1], lo, hi);
    float s = (float)(tot2[0] / tot2[1]);
    const int n4 = NW / 4;
    const float4* w4 = (const float4*)w;
    for (int i = blockIdx.x * blockDim.x + threadIdx.x; i < n4;
         i += gridDim.x * blockDim.x) {
        float4 v = w4[i];
        ushort4 h, l;
        split1(v.x, lo, hi, s, h.x, l.x);
        split1(v.y, lo, hi, s, h.y, l.y);
        split1(v.z, lo, hi, s, h.z, l.z);
        split1(v.w, lo, hi, s, h.w, l.w);
        Whi[i] = h; Wlo[i] = l;
    }
}

// ================= GEMM =================
// out = Xh@Wh^T + Xl@Wh^T + Xh@Wl^T + bias
// 128x128 tile, BK=32, 4 waves (2x2), 4 matrices staged, explicit double-buffer
// (2 x 4 x 8KB = 64KB LDS -> 2 blocks/CU). T3/T4 minimum pipeline: per K-tile
// {STAGE(next) -> ds_read(cur)+MFMA -> syncthreads}: the vmcnt(0) drain inside
// syncthreads now sits AFTER compute, so in-flight loads hide under MFMA.
// Both-sides XOR swizzle (rule #21): 64B rows = 4 x 16B slots; source slot
// q = (l&3) ^ ((l>>3)&3) pre-applied on GLOBAL addr (LDS dest linear); reader
// uses physical slot fk ^ ((fcol>>1)&3). 2 lanes/bank-quad = conflict-free.
#define GEMM_NWG   ((MROWS / 128) * (D_OUT / 128))   // 2048
#define NT_K       (D_IN / 32)                        // 128 K-tiles

__global__ __launch_bounds__(256, 2) void k_gemm(
    const unsigned short* __restrict__ Xh, const unsigned short* __restrict__ Xl,
    const unsigned short* __restrict__ Wh, const unsigned short* __restrict__ Wl,
    const float* __restrict__ bias, float* __restrict__ out)
{
    __shared__ unsigned short lds[2 * 4 * 128 * 32];   // [buf][mat][128r x 32c]
#define LBASE(B, M) (&lds[(((B) * 4 + (M))) * 4096])

    // XCD swizzle + 8x8 inner tiling (bijective): xcd slab = 8 by-rows; within
    // slab, co-resident blocks form 8x8 panels (8 A + 8 B hot, not 2 + 32).
    const int bid   = blockIdx.x;
    const int xcd   = bid & 7;
    const int local = bid >> 3;              // 0..255
    const int quad  = local >> 6;            // 0..3
    const int byl   = (local >> 3) & 7;
    const int bxl   = local & 7;
    const int bx    = quad * 8 + bxl;        // 0..31
    const int by    = xcd * 8 + byl;         // 0..63

    const int tid  = threadIdx.x;
    const int wave = tid >> 6, lane = tid & 63;
    const int wr = wave >> 1, wc = wave & 1;
    const int fcol = lane & 15, fk = lane >> 4;        // fk = 0..3 (k-slot)
    const int pslot = fk ^ ((fcol >> 1) & 3);          // swizzled read slot
    const int brow = by * 128, bcol = bx * 128;

    f32x4v acc[4][4];
    const f32x4v zero = {0.f, 0.f, 0.f, 0.f};
#pragma unroll
    for (int m = 0; m < 4; m++)
#pragma unroll
        for (int n = 0; n < 4; n++) acc[m][n] = zero;

    const unsigned short* Agh = Xh + (size_t)brow * D_IN;
    const unsigned short* Agl = Xl + (size_t)brow * D_IN;
    const unsigned short* Bgh = Wh + (size_t)bcol * D_IN;
    const unsigned short* Bgl = Wl + (size_t)bcol * D_IN;

    const int sr = lane >> 2;                          // 0..15 row in 16-row chunk
    const int sq = (lane & 3) ^ ((lane >> 3) & 3);     // pre-swizzled source slot

#define STAGE(B, kk) do {                                                   \
    _Pragma("unroll")                                                       \
    for (int i = 0; i < 2; i++) {                                           \
        const int rr = wave * 32 + i * 16;                                  \
        const size_t go = (size_t)(rr + sr) * D_IN + (kk) + sq * 8;         \
        const int lo = rr * 64;  /* 64B rows, linear dest */                \
        gload_lds16(Agh + go, (char*)LBASE(B, 0) + lo);                     \
        gload_lds16(Agl + go, (char*)LBASE(B, 1) + lo);                     \
        gload_lds16(Bgh + go, (char*)LBASE(B, 2) + lo);                     \
        gload_lds16(Bgl + go, (char*)LBASE(B, 3) + lo);                     \
    } } while (0)

#define KSTEP(B) do {                                                       \
    const unsigned short* Lah = LBASE(B, 0);                                \
    const unsigned short* Lal = LBASE(B, 1);                                \
    const unsigned short* Lbh = LBASE(B, 2);                                \
    const unsigned short* Lbl = LBASE(B, 3);                                \
    bf16x8 ah[4], al[4], bh[4], bl[4];                                      \
    _Pragma("unroll")                                                       \
    for (int m = 0; m < 4; m++) {                                           \
        const int ro = (wr * 64 + m * 16 + fcol) * 32 + pslot * 8;          \
        ah[m] = *(const bf16x8*)&Lah[ro];                                   \
        al[m] = *(const bf16x8*)&Lal[ro];                                   \
    }                                                                       \
    _Pragma("unroll")                                                       \
    for (int n = 0; n < 4; n++) {                                           \
        const int ro = (wc * 64 + n * 16 + fcol) * 32 + pslot * 8;          \
        bh[n] = *(const bf16x8*)&Lbh[ro];                                   \
        bl[n] = *(const bf16x8*)&Lbl[ro];                                   \
    }                                                                       \
    __builtin_amdgcn_s_setprio(1);                                          \
    _Pragma("unroll")                                                       \
    for (int m = 0; m < 4; m++)                                             \
        _Pragma("unroll")                                                   \
        for (int n = 0; n < 4; n++) {                                       \
            acc[m][n] = __builtin_amdgcn_mfma_f32_16x16x32_bf16(            \
                ah[m], bh[n], acc[m][n], 0, 0, 0);                          \
            acc[m][n] = __builtin_amdgcn_mfma_f32_16x16x32_bf16(            \
                al[m], bh[n], acc[m][n], 0, 0, 0);                          \
            acc[m][n] = __builtin_amdgcn_mfma_f32_16x16x32_bf16(            \
                ah[m], bl[n], acc[m][n], 0, 0, 0);                          \
        }                                                                   \
    __builtin_amdgcn_s_setprio(0);                                          \
    } while (0)

    // prologue
    STAGE(0, 0);
    __syncthreads();
    int cur = 0;
    for (int t = 0; t < NT_K - 1; ++t) {
        STAGE(cur ^ 1, (t + 1) * 32);   // issue next-tile loads FIRST
        KSTEP(cur);                      // compute current (loads fly underneath)
        __syncthreads();                 // drain (after compute) + barrier
        cur ^= 1;
    }
    KSTEP(cur);                          // epilogue tile, no prefetch

    // epilogue: C/D mapping col=lane&15, row=(lane>>4)*4+reg  [m89-verified]
#pragma unroll
    for (int n = 0; n < 4; n++) {
        int col = bcol + wc * 64 + n * 16 + fcol;
        float bv = bias[col];
#pragma unroll
        for (int m = 0; m < 4; m++) {
            int row = brow + wr * 64 + m * 16 + fk * 4;
            float* o = out + (size_t)row * D_OUT + col;
#pragma unroll
            for (int r = 0; r < 4; r++) o[(size_t)r * D_OUT] = acc[m][n][r] + bv;
        }
    }
#undef STAGE
#undef KSTEP
#undef LBASE
}

// ---------- launch ----------
extern "C" void kernel_launch(void* const* d_in, const int* in_sizes, int n_in,
                              void* d_out, int out_size, void* d_ws, size_t ws_size,
                              hipStream_t stream) {
    const float* x    = (const float*)d_in[0];   // [8192, 4096]
    const float* w    = (const float*)d_in[1];   // [4096, 4096]
    const float* bias = (const float*)d_in[2];   // [4096]
    float* out = (float*)d_out;                  // [8192, 4096]

    char* ws = (char*)d_ws;
    double* part1 = (double*)ws;                         // 512*2 doubles
    double* part2 = part1 + 2 * ST_BLK;                  // 512*2 doubles
    unsigned short* Whi = (unsigned short*)(ws + 65536);            // 32 MiB
    unsigned short* Wlo = Whi + (size_t)NW;                         // 32 MiB
    unsigned short* Xh  = Wlo + (size_t)NW;                         // 64 MiB
    unsigned short* Xl  = Xh + (size_t)NX;                          // 64 MiB

    k_pre1  <<<ST_BLK + XS_BLK, 256, 0, stream>>>(w, x, part1,
                                                  (ushort4*)Xh, (ushort4*)Xl);
    k_stats2<<<ST_BLK, 256, 0, stream>>>(w, part1, part2);
    k_wsplit<<<1024, 256, 0, stream>>>(w, part1, part2,
                                       (ushort4*)Whi, (ushort4*)Wlo);
    k_gemm<<<GEMM_NWG, 256, 0, stream>>>(Xh, Xl, Whi, Wlo, bias, out);
}

// Round 9
// 802.905 us; speedup vs baseline: 1.5657x; 1.2657x over previous
//
#include <hip/hip_runtime.h>
#include <stdint.h>

#define D_IN   4096
#define D_OUT  4096
#define MROWS  8192                  // 4 * 2048
#define NW     (D_OUT * D_IN)        // 16777216 weight elements
#define NX     (MROWS * D_IN)        // 33554432 x elements
#define STD_K  1.6

typedef float  f32x4v  __attribute__((ext_vector_type(4)));
typedef __bf16 bf16x8  __attribute__((ext_vector_type(8)));

// ---------- bf16 helpers (RNE) ----------
__device__ __forceinline__ unsigned short f2bf(float f) {
    unsigned int u = __float_as_uint(f);
    u = u + 0x7fffu + ((u >> 16) & 1u);
    return (unsigned short)(u >> 16);
}
__device__ __forceinline__ float bf2f(unsigned short b) {
    return __uint_as_float(((unsigned int)b) << 16);
}

// ---------- async global->LDS (16B/lane, dest = wave-uniform base + lane*16) ----------
__device__ __forceinline__ void gload_lds16(const void* g, void* l) {
    __builtin_amdgcn_global_load_lds(
        (__attribute__((address_space(1))) void*)(void*)(g),
        (__attribute__((address_space(3))) void*)(l),
        16, 0, 0);
}

// ================= preprocessing (atomic-free) =================
#define ST_BLK 512
#define XS_BLK 1536
// pre1: blocks [0,512) stats1 partials over w; blocks [512,2048) xsplit.
__global__ void k_pre1(const float* __restrict__ w, const float* __restrict__ x,
                       double* __restrict__ part1,
                       ushort4* __restrict__ Xh, ushort4* __restrict__ Xl) {
    __shared__ double red[8];
    const int tid = threadIdx.x;
    if (blockIdx.x < ST_BLK) {
        const int n4 = NW / 4;
        const float4* w4 = (const float4*)w;
        double s = 0.0, s2 = 0.0;
        for (int i = blockIdx.x * 256 + tid; i < n4; i += ST_BLK * 256) {
            float4 v = w4[i];
            s  += (double)v.x + (double)v.y + (double)v.z + (double)v.w;
            s2 += (double)v.x * (double)v.x + (double)v.y * (double)v.y +
                  (double)v.z * (double)v.z + (double)v.w * (double)v.w;
        }
        for (int o = 32; o; o >>= 1) { s += __shfl_down(s, o); s2 += __shfl_down(s2, o); }
        const int wave = tid >> 6, lane = tid & 63;
        if (lane == 0) { red[wave] = s; red[4 + wave] = s2; }
        __syncthreads();
        if (tid == 0) {
            part1[2 * blockIdx.x]     = red[0] + red[1] + red[2] + red[3];
            part1[2 * blockIdx.x + 1] = red[4] + red[5] + red[6] + red[7];
        }
    } else {
        const int n4 = NX / 4;
        const float4* x4 = (const float4*)x;
        for (int i = (blockIdx.x - ST_BLK) * 256 + tid; i < n4; i += XS_BLK * 256) {
            float4 v = x4[i];
            ushort4 h, l;
            h.x = f2bf(v.x); l.x = f2bf(v.x - bf2f(h.x));
            h.y = f2bf(v.y); l.y = f2bf(v.y - bf2f(h.y));
            h.z = f2bf(v.z); l.z = f2bf(v.z - bf2f(h.z));
            h.w = f2bf(v.w); l.w = f2bf(v.w - bf2f(h.w));
            Xh[i] = h; Xl[i] = l;
        }
    }
}

// in-block reduction of a [n][2] partial array -> tot[0], tot[1]
__device__ __forceinline__ void reduce_parts(const double* __restrict__ part, int n,
                                             double* __restrict__ tot,
                                             double* __restrict__ red) {
    const int tid = threadIdx.x;
    double s = 0.0, s2 = 0.0;
    for (int i = tid; i < n; i += 256) { s += part[2 * i]; s2 += part[2 * i + 1]; }
    for (int o = 32; o; o >>= 1) { s += __shfl_down(s, o); s2 += __shfl_down(s2, o); }
    const int wave = tid >> 6, lane = tid & 63;
    if (lane == 0) { red[wave] = s; red[4 + wave] = s2; }
    __syncthreads();
    if (tid == 0) {
        tot[0] = red[0] + red[1] + red[2] + red[3];
        tot[1] = red[4] + red[5] + red[6] + red[7];
    }
    __syncthreads();
}

__device__ __forceinline__ void thr_from(double s0, double s1, double& lo, double& hi) {
    const double n = (double)NW;
    double mean = s0 / n;
    double var  = (s1 - s0 * mean) / (n - 1.0);   // ddof=1
    double sd   = sqrt(var);
    lo = mean - STD_K * sd;
    hi = mean + STD_K * sd;
}

// stats2: reduce part1 in-block, then sum(|w|*keep), count(keep) partials
__global__ void k_stats2(const float* __restrict__ w, const double* __restrict__ part1,
                         double* __restrict__ part2) {
    __shared__ double red[8];
    __shared__ double tot[2];
    reduce_parts(part1, ST_BLK, tot, red);
    double lo, hi;
    thr_from(tot[0], tot[1], lo, hi);
    const int n4 = NW / 4;
    const float4* w4 = (const float4*)w;
    double sa = 0.0, cnt = 0.0;
#define ACC1(X) { bool keep = ((double)(X) >= lo) && ((double)(X) <= hi); \
                  if (keep) { sa += (double)fabsf(X); cnt += 1.0; } }
    for (int i = blockIdx.x * 256 + threadIdx.x; i < n4; i += ST_BLK * 256) {
        float4 v = w4[i];
        ACC1(v.x) ACC1(v.y) ACC1(v.z) ACC1(v.w)
    }
#undef ACC1
    for (int o = 32; o; o >>= 1) { sa += __shfl_down(sa, o); cnt += __shfl_down(cnt, o); }
    __syncthreads();
    const int wave = threadIdx.x >> 6, lane = threadIdx.x & 63;
    if (lane == 0) { red[wave] = sa; red[4 + wave] = cnt; }
    __syncthreads();
    if (threadIdx.x == 0) {
        part2[2 * blockIdx.x]     = red[0] + red[1] + red[2] + red[3];
        part2[2 * blockIdx.x + 1] = red[4] + red[5] + red[6] + red[7];
    }
}

// wprep: W' = w_sim / s  ->  +-1 EXACT in bf16 for non-outliers (89%),
// w/s (bf16-rounded) for outliers. Also publishes s for the GEMM epilogue.
__global__ void k_wprep(const float* __restrict__ w, const double* __restrict__ part1,
                        const double* __restrict__ part2,
                        ushort4* __restrict__ Wp, float* __restrict__ sval) {
    __shared__ double red[8];
    __shared__ double tot1[2];
    __shared__ double tot2[2];
    reduce_parts(part1, ST_BLK, tot1, red);
    __syncthreads();
    reduce_parts(part2, ST_BLK, tot2, red);
    double lo, hi;
    thr_from(tot1[0], tot1[1], lo, hi);
    const double s = tot2[0] / tot2[1];
    if (blockIdx.x == 0 && threadIdx.x == 0) *sval = (float)s;
#define SPLIT1(X, H) {                                                        \
    bool outl = ((double)(X) < lo) || ((double)(X) > hi);                     \
    float sg1 = ((X) > 0.f) ? 1.f : (((X) < 0.f) ? -1.f : 0.f);               \
    float wp  = outl ? (float)((double)(X) / s) : sg1;                        \
    H = f2bf(wp); }
    const int n4 = NW / 4;
    const float4* w4 = (const float4*)w;
    for (int i = blockIdx.x * blockDim.x + threadIdx.x; i < n4;
         i += gridDim.x * blockDim.x) {
        float4 v = w4[i];
        ushort4 h;
        SPLIT1(v.x, h.x) SPLIT1(v.y, h.y) SPLIT1(v.z, h.z) SPLIT1(v.w, h.w)
        Wp[i] = h;
    }
#undef SPLIT1
}

// ================= GEMM =================
// out = s * (Xh@Wp^T + Xl@Wp^T) + bias      (Wp = w_sim / s, see k_wprep)
// 128x128 tile, BK=32, 4 waves (2x2), 3 matrices staged (Ah, Al, B), explicit
// double-buffer: 2 x 3 x 8KB = 48KB LDS -> 3 blocks/CU (independent barriers
// de-stagger waves). Pipeline: {STAGE(next) -> ds_read(cur)+MFMA -> barrier}.
// Both-sides XOR swizzle (rule #21), re-derived for 64B rows: chunk(mod 8) =
// 4*(row&1) + p; staging p=l&3, sq=(l&3)^((l>>3)&3); reader pslot =
// fk^((fcol>>1)&3). Per 8-lane HW group all 32 banks covered exactly once.
#define GEMM_NWG   ((MROWS / 128) * (D_OUT / 128))   // 2048
#define NT_K       (D_IN / 32)                        // 128 K-tiles

__global__ __launch_bounds__(256, 3) void k_gemm(
    const unsigned short* __restrict__ Xh, const unsigned short* __restrict__ Xl,
    const unsigned short* __restrict__ Wp, const float* __restrict__ sval,
    const float* __restrict__ bias, float* __restrict__ out)
{
    __shared__ unsigned short lds[2 * 3 * 128 * 32];   // [buf][mat][128r x 32c]
#define LBASE(B, M) (&lds[(((B) * 3 + (M))) * 4096])

    // XCD swizzle + 8x8 inner tiling (bijective, 2048 % 8 == 0)
    const int bid   = blockIdx.x;
    const int xcd   = bid & 7;
    const int local = bid >> 3;              // 0..255
    const int quad  = local >> 6;            // 0..3
    const int byl   = (local >> 3) & 7;
    const int bxl   = local & 7;
    const int bx    = quad * 8 + bxl;        // 0..31
    const int by    = xcd * 8 + byl;         // 0..63

    const int tid  = threadIdx.x;
    const int wave = tid >> 6, lane = tid & 63;
    const int wr = wave >> 1, wc = wave & 1;
    const int fcol = lane & 15, fk = lane >> 4;        // fk = 0..3 (k-slot)
    const int pslot = fk ^ ((fcol >> 1) & 3);          // swizzled read slot
    const int brow = by * 128, bcol = bx * 128;

    f32x4v acc[4][4];
    const f32x4v zero = {0.f, 0.f, 0.f, 0.f};
#pragma unroll
    for (int m = 0; m < 4; m++)
#pragma unroll
        for (int n = 0; n < 4; n++) acc[m][n] = zero;

    const unsigned short* Agh = Xh + (size_t)brow * D_IN;
    const unsigned short* Agl = Xl + (size_t)brow * D_IN;
    const unsigned short* Bg  = Wp + (size_t)bcol * D_IN;

    const int sr = lane >> 2;                          // 0..15 row in 16-row chunk
    const int sq = (lane & 3) ^ ((lane >> 3) & 3);     // pre-swizzled source slot

#define STAGE(B, kk) do {                                                   \
    _Pragma("unroll")                                                       \
    for (int i = 0; i < 2; i++) {                                           \
        const int rr = wave * 32 + i * 16;                                  \
        const size_t go = (size_t)(rr + sr) * D_IN + (kk) + sq * 8;         \
        const int lo = rr * 64;  /* 64B rows, linear dest */                \
        gload_lds16(Agh + go, (char*)LBASE(B, 0) + lo);                     \
        gload_lds16(Agl + go, (char*)LBASE(B, 1) + lo);                     \
        gload_lds16(Bg  + go, (char*)LBASE(B, 2) + lo);                     \
    } } while (0)

#define KSTEP(B) do {                                                       \
    const unsigned short* Lah = LBASE(B, 0);                                \
    const unsigned short* Lal = LBASE(B, 1);                                \
    const unsigned short* Lb  = LBASE(B, 2);                                \
    bf16x8 ah[4], al[4], b[4];                                              \
    _Pragma("unroll")                                                       \
    for (int m = 0; m < 4; m++) {                                           \
        const int ro = (wr * 64 + m * 16 + fcol) * 32 + pslot * 8;          \
        ah[m] = *(const bf16x8*)&Lah[ro];                                   \
        al[m] = *(const bf16x8*)&Lal[ro];                                   \
    }                                                                       \
    _Pragma("unroll")                                                       \
    for (int n = 0; n < 4; n++) {                                           \
        const int ro = (wc * 64 + n * 16 + fcol) * 32 + pslot * 8;          \
        b[n] = *(const bf16x8*)&Lb[ro];                                     \
    }                                                                       \
    __builtin_amdgcn_s_setprio(1);                                          \
    _Pragma("unroll")                                                       \
    for (int m = 0; m < 4; m++)                                             \
        _Pragma("unroll")                                                   \
        for (int n = 0; n < 4; n++) {                                       \
            acc[m][n] = __builtin_amdgcn_mfma_f32_16x16x32_bf16(            \
                ah[m], b[n], acc[m][n], 0, 0, 0);                           \
            acc[m][n] = __builtin_amdgcn_mfma_f32_16x16x32_bf16(            \
                al[m], b[n], acc[m][n], 0, 0, 0);                           \
        }                                                                   \
    __builtin_amdgcn_s_setprio(0);                                          \
    } while (0)

    // prologue
    STAGE(0, 0);
    __syncthreads();
    int cur = 0;
    for (int t = 0; t < NT_K - 1; ++t) {
        STAGE(cur ^ 1, (t + 1) * 32);   // issue next-tile loads FIRST
        KSTEP(cur);                      // compute current (loads fly underneath)
        __syncthreads();                 // drain (after compute) + barrier
        cur ^= 1;
    }
    KSTEP(cur);                          // last tile, no prefetch

    // epilogue: out = s*acc + bias; C/D map col=lane&15, row=(lane>>4)*4+reg
    const float sf = *sval;
#pragma unroll
    for (int n = 0; n < 4; n++) {
        int col = bcol + wc * 64 + n * 16 + fcol;
        float bv = bias[col];
#pragma unroll
        for (int m = 0; m < 4; m++) {
            int row = brow + wr * 64 + m * 16 + fk * 4;
            float* o = out + (size_t)row * D_OUT + col;
#pragma unroll
            for (int r = 0; r < 4; r++) o[(size_t)r * D_OUT] = sf * acc[m][n][r] + bv;
        }
    }
#undef STAGE
#undef KSTEP
#undef LBASE
}

// ---------- launch ----------
extern "C" void kernel_launch(void* const* d_in, const int* in_sizes, int n_in,
                              void* d_out, int out_size, void* d_ws, size_t ws_size,
                              hipStream_t stream) {
    const float* x    = (const float*)d_in[0];   // [8192, 4096]
    const float* w    = (const float*)d_in[1];   // [4096, 4096]
    const float* bias = (const float*)d_in[2];   // [4096]
    float* out = (float*)d_out;                  // [8192, 4096]

    char* ws = (char*)d_ws;
    double* part1 = (double*)ws;                         // 512*2 doubles
    double* part2 = part1 + 2 * ST_BLK;                  // 512*2 doubles
    float*  sval  = (float*)(part2 + 2 * ST_BLK);        // 1 float
    unsigned short* Wp = (unsigned short*)(ws + 65536);             // 32 MiB
    unsigned short* Xh = Wp + (size_t)NW;                           // 64 MiB
    unsigned short* Xl = Xh + (size_t)NX;                           // 64 MiB

    k_pre1  <<<ST_BLK + XS_BLK, 256, 0, stream>>>(w, x, part1,
                                                  (ushort4*)Xh, (ushort4*)Xl);
    k_stats2<<<ST_BLK, 256, 0, stream>>>(w, part1, part2);
    k_wprep <<<1024, 256, 0, stream>>>(w, part1, part2, (ushort4*)Wp, sval);
    k_gemm<<<GEMM_NWG, 256, 0, stream>>>(Xh, Xl, Wp, sval, bias, out);
}